// Round 12
// baseline (41.202 us; speedup 1.0000x reference)
//
#include <hip/hip_runtime.h>
#include <hip/hip_fp16.h>
#include <math.h>

#define HW 16384
#define NPROJ 100
#define NB 8
#define NCH 32
#define CHLEN 512
#define EPSV 1e-6f

__device__ inline unsigned int packh2(float a, float b) {
    __half2 h = __floats2half2_rn(a, b);
    return *reinterpret_cast<unsigned int*>(&h);
}
__device__ inline float2 unpackh2(unsigned int w) {
    __half2 h = *reinterpret_cast<__half2*>(&w);
    return make_float2(__low2float(h), __high2float(h));
}

// Stage 1: per-(batch, chunk) partials: Xs = x0+x1+x2 (stored), sum(Xs), sum(y0),
// chunk max/argmax of x0 (first-occurrence). Block 0 zeroes the output.
__global__ __launch_bounds__(256) void partial_kernel(const float* __restrict__ X,
                                                      const float* __restrict__ Y,
                                                      float* __restrict__ Xs,
                                                      float* __restrict__ Pmax,
                                                      int* __restrict__ Pidx,
                                                      float* __restrict__ Psx,
                                                      float* __restrict__ Psy,
                                                      float* __restrict__ out) {
    const int blk = blockIdx.x;
    const int b = blk >> 5, c = blk & 31;
    const int tid = threadIdx.x, lane = tid & 63, wid = tid >> 6;
    if (blk == 0 && tid == 0) out[0] = 0.0f;  // consumed only by wproj (later kernel)
    const float* xb = X + (size_t)b * 3 * HW;
    const float* yb = Y + (size_t)b * 3 * HW;
    const int base = c * CHLEN;

    float mv = -INFINITY;
    int mi = 0;
    float sx = 0.0f, sy = 0.0f;
#pragma unroll
    for (int k = 0; k < 2; ++k) {
        int p = base + k * 256 + tid;
        float x0 = xb[p], x1 = xb[HW + p], x2 = xb[2 * HW + p], y0 = yb[p];
        float s = x0 + x1 + x2;
        Xs[(size_t)b * HW + p] = s;
        sx += s;
        sy += y0;
        if (x0 > mv) { mv = x0; mi = p; }   // strict > keeps earliest p
    }
#pragma unroll
    for (int off = 32; off > 0; off >>= 1) {
        float ov = __shfl_down(mv, off);
        int oi = __shfl_down(mi, off);
        sx += __shfl_down(sx, off);
        sy += __shfl_down(sy, off);
        if (ov > mv || (ov == mv && oi < mi)) { mv = ov; mi = oi; }
    }
    __shared__ float lmv[4], lsx[4], lsy[4];
    __shared__ int lmi[4];
    if (lane == 0) { lmv[wid] = mv; lmi[wid] = mi; lsx[wid] = sx; lsy[wid] = sy; }
    __syncthreads();
    if (tid == 0) {
        for (int w = 1; w < 4; ++w) {
            if (lmv[w] > lmv[0] || (lmv[w] == lmv[0] && lmi[w] < lmi[0])) {
                lmv[0] = lmv[w];
                lmi[0] = lmi[w];
            }
            lsx[0] += lsx[w];
            lsy[0] += lsy[w];
        }
        Pmax[blk] = lmv[0];
        Pidx[blk] = lmi[0];
        Psx[blk] = lsx[0];
        Psy[blk] = lsy[0];
    }
}

// Stage 2 (combine folded in): builds two channel-half tables:
// Zr[h*HW + p] = uint2 of 4 packed fp16: z[4h..4h+3](p). All coalesced.
__global__ __launch_bounds__(256) void zprep_kernel(const float* __restrict__ Pmax,
                                                    const int* __restrict__ Pidx,
                                                    const float* __restrict__ Psx,
                                                    const float* __restrict__ Psy,
                                                    const float* __restrict__ Xs,
                                                    const float* __restrict__ Y,
                                                    uint2* __restrict__ Zr) {
    __shared__ float sInvX[8], sInvY[8], sFa[8];
    __shared__ int sFi[8];
    const int tid = threadIdx.x;
    const int c = tid & 31;
    {
        const int b = tid >> 5;
        float mv = Pmax[tid];
        int mi = Pidx[tid];
        float sx = Psx[tid];
        float sy = Psy[tid];
#pragma unroll
        for (int off = 16; off > 0; off >>= 1) {
            float ov = __shfl_down(mv, off, 32);
            int oi = __shfl_down(mi, off, 32);
            float osx = __shfl_down(sx, off, 32);
            float osy = __shfl_down(sy, off, 32);
            if (ov > mv || (ov == mv && oi < mi)) { mv = ov; mi = oi; }
            sx += osx;
            sy += osy;
        }
        if (c == 0) {
            float fa = (mv < EPSV) ? (EPSV - mv) : 0.0f;
            sFa[b] = fa;
            sFi[b] = mi;
            sInvX[b] = 1.0f / (sx + fa);
            sInvY[b] = 1.0f / sy;
        }
    }
    __syncthreads();
    const int p = blockIdx.x * 256 + tid;
    float z[8];
#pragma unroll
    for (int b = 0; b < 8; ++b) {
        float s = Xs[(size_t)b * HW + p];
        if (p == sFi[b]) s += sFa[b];
        z[b] = s * sInvX[b] - Y[(size_t)b * 3 * HW + p] * sInvY[b];
    }
    Zr[p] = make_uint2(packh2(z[0], z[1]), packh2(z[2], z[3]));
    Zr[HW + p] = make_uint2(packh2(z[4], z[5]), packh2(z[6], z[7]));
}

// Block = (projection, channel-half). Phase 1: analytic ranksort -> transposed
// sidT (32 KiB). ids+dpc pulled to registers, then the SAME LDS region is
// overwritten by a coalesced stage of the 128 KiB channel-half Z table.
// Phase 2: full-range in-block scan (no cross-block carry); gathers are
// ds_read_b32 from LDS (no divergent VMEM anywhere). 2 sub-passes x 2 channels.
__global__ __launch_bounds__(1024)
__attribute__((amdgpu_waves_per_eu(4, 4)))
void wproj_kernel(const float* __restrict__ proj,
                  const uint2* __restrict__ Zr,
                  float* __restrict__ out) {
    __shared__ unsigned int smem32[32768 + 48];  // 128 KiB union + scan scratch
    unsigned int* zlds = smem32;                                  // phase 2
    unsigned short* sidT = (unsigned short*)smem32;               // phase 1 (32 KiB)
    int* c_t = (int*)(smem32 + 8192);                             // phase 1 (255)
    unsigned char* e_t = (unsigned char*)(smem32 + 8192 + 255);   // phase 1 (255 B)
    float2* lw = (float2*)(smem32 + 32768);                       // 16 float2
    float* lred = (float*)(smem32 + 32768 + 32);                  // 16 floats

    const int jp = blockIdx.x >> 1;
    const int h = blockIdx.x & 1;
    const int tid = threadIdx.x, lane = tid & 63, wid = tid >> 6;
    float a = proj[jp];
    float b = proj[NPROJ + jp];
    float inv = 1.0f / sqrtf(a * a + b * b);
    const float an = a * inv, bn = b * inv;
    const float ap = fabsf(an), bp = fabsf(bn);
    const bool flipi = (an < 0.0f), flipj = (bn < 0.0f);

    // ---- phase 1: ranksort into transposed sidT (pos = tid*16 + m) ----
    if (bp == 0.0f) {
        for (int t = tid; t < HW; t += 1024) {
            int i2 = t >> 7, j2 = t & 127;
            int ii = flipi ? 127 - i2 : i2;
            int jj = flipj ? 127 - j2 : j2;
            sidT[(t & 15) * 1024 + (t >> 4)] = (unsigned short)(ii * 128 + jj);
        }
    } else {
        if (tid < 255) {
            int d = tid - 127;
            double v = (double)d * ((double)ap / (double)bp);
            double cv = ceil(v);
            e_t[tid] = (cv == v) ? 1 : 0;
            c_t[tid] = (int)fmin(fmax(cv, -128.0), 129.0);
        }
        __syncthreads();
        {
            const int j2 = tid & 127;
            const int g = tid >> 7;          // 0..7, each covers 16 rows of i2
            const int i2s = g * 16;
            const int jj = flipj ? 127 - j2 : j2;

            int wsum = 0;
#pragma unroll 8
            for (int q = 0; q < 128; ++q)
                wsum += min(max(c_t[i2s + q] + j2, 0), 128);
            int tsum = 0;
            for (int i2p = 1; i2p <= i2s; ++i2p) {
                if (e_t[i2p + 127]) {
                    int tj = j2 + c_t[i2p + 127];
                    if (tj >= 0 && tj < 128) tsum++;
                }
            }
            for (int q = 0; q < 16; ++q) {
                int i2 = i2s + q;
                if (q > 0) {
                    int dd_new = i2 + 127;
                    int dd_old = i2 - 1;
                    int cn = c_t[dd_new];
                    wsum += min(max(cn + j2, 0), 128);
                    wsum -= min(max(c_t[dd_old] + j2, 0), 128);
                    if (e_t[dd_new]) {
                        int tj = j2 + cn;
                        if (tj >= 0 && tj < 128) tsum++;
                    }
                }
                int pos = wsum + tsum;
                int ii = flipi ? 127 - i2 : i2;
                sidT[(pos & 15) * 1024 + (pos >> 4)] =
                    (unsigned short)(ii * 128 + jj);
            }
        }
    }
    __syncthreads();

    // ---- pull ids to registers; compute dpc; then free sidT for staging ----
    int ids[17];
#pragma unroll
    for (int m = 0; m < 16; ++m) ids[m] = (int)sidT[m * 1024 + tid];
    ids[16] = (tid < 1023) ? (int)sidT[tid + 1] : ids[15];
    __syncthreads();  // all sidT reads done before overwrite

    float dpc[16];
    {
        float pc_cur = (float)(ids[0] >> 7) * an + (float)(ids[0] & 127) * bn;
#pragma unroll
        for (int m = 0; m < 16; ++m) {
            int idn = ids[m + 1];
            float pc_nxt = (float)(idn >> 7) * an + (float)(idn & 127) * bn;
            dpc[m] = (tid * 16 + m < HW - 1) ? (pc_nxt - pc_cur) : 0.0f;
            pc_cur = pc_nxt;
        }
    }

    // ---- stage the 128 KiB channel-half table into LDS (coalesced) ----
    {
        const uint4* s4 = (const uint4*)(Zr + (size_t)h * HW);
        uint4* d4 = (uint4*)zlds;
#pragma unroll
        for (int it = 0; it < 8; ++it)
            d4[it * 1024 + tid] = s4[it * 1024 + tid];
    }
    __syncthreads();

    // ---- phase 2: 2 sub-passes x 2 channels, full-range in-block scan ----
    float acc = 0.0f;
#pragma unroll 1
    for (int sp = 0; sp < 2; ++sp) {
        float2 zv[16];
#pragma unroll
        for (int m = 0; m < 16; ++m) {
            unsigned int w = zlds[ids[m] * 2 + sp];
            zv[m] = unpackh2(w);
        }
#pragma unroll
        for (int m = 1; m < 16; ++m) {
            zv[m].x += zv[m - 1].x;
            zv[m].y += zv[m - 1].y;
        }
        const float2 tot = zv[15];

        float2 ia = tot;
#pragma unroll
        for (int off = 1; off < 64; off <<= 1) {
            float ux = __shfl_up(ia.x, off);
            float uy = __shfl_up(ia.y, off);
            if (lane >= off) { ia.x += ux; ia.y += uy; }
        }
        if (lane == 63) lw[wid] = ia;
        __syncthreads();

        float2 pre = make_float2(ia.x - tot.x, ia.y - tot.y);
#pragma unroll
        for (int w = 0; w < 16; ++w) {
            if (w < wid) {
                float2 t = lw[w];
                pre.x += t.x;
                pre.y += t.y;
            }
        }

#pragma unroll
        for (int m = 0; m < 16; ++m) {
            float cx = pre.x + zv[m].x;
            float cy = pre.y + zv[m].y;
            acc += (fabsf(cx) + fabsf(cy)) * dpc[m];
        }
        __syncthreads();  // lw reuse next sub-pass
    }

    // block reduce
#pragma unroll
    for (int off = 32; off > 0; off >>= 1) acc += __shfl_down(acc, off);
    if (lane == 0) lred[wid] = acc;
    __syncthreads();
    if (tid == 0) {
        float r = 0.0f;
        for (int w = 0; w < 16; ++w) r += lred[w];
        atomicAdd(out, r * (1.0f / NPROJ));
    }
}

extern "C" void kernel_launch(void* const* d_in, const int* in_sizes, int n_in,
                              void* d_out, int out_size, void* d_ws, size_t ws_size,
                              hipStream_t stream) {
    const float* X = (const float*)d_in[0];
    const float* Y = (const float*)d_in[1];
    const float* proj = (const float*)d_in[2];
    float* out = (float*)d_out;

    char* ws = (char*)d_ws;
    size_t off = 0;
    float* Xs = (float*)(ws + off);     off += (size_t)NB * HW * sizeof(float);
    uint2* Zr = (uint2*)(ws + off);     off += (size_t)2 * HW * sizeof(uint2);
    float* Pmax = (float*)(ws + off);   off += NB * NCH * sizeof(float);
    int* Pidx = (int*)(ws + off);       off += NB * NCH * sizeof(int);
    float* Psx = (float*)(ws + off);    off += NB * NCH * sizeof(float);
    float* Psy = (float*)(ws + off);    off += NB * NCH * sizeof(float);

    partial_kernel<<<NB * NCH, 256, 0, stream>>>(X, Y, Xs, Pmax, Pidx, Psx, Psy, out);
    zprep_kernel<<<HW / 256, 256, 0, stream>>>(Pmax, Pidx, Psx, Psy, Xs, Y, Zr);
    wproj_kernel<<<NPROJ * 2, 1024, 0, stream>>>(proj, Zr, out);
}

// Round 13
// 28.296 us; speedup vs baseline: 1.4561x; 1.4561x over previous
//
#include <hip/hip_runtime.h>
#include <hip/hip_fp16.h>
#include <math.h>

#define HW 16384
#define NPROJ 100
#define NB 8
#define NCH 32
#define CHLEN 512
#define EPSV 1e-6f

__device__ inline float4 add4(float4 a, float4 b) {
    return make_float4(a.x + b.x, a.y + b.y, a.z + b.z, a.w + b.w);
}
__device__ inline float4 sub4(float4 a, float4 b) {
    return make_float4(a.x - b.x, a.y - b.y, a.z - b.z, a.w - b.w);
}
__device__ inline float4 shfl_up4(float4 v, int off) {
    return make_float4(__shfl_up(v.x, off), __shfl_up(v.y, off),
                       __shfl_up(v.z, off), __shfl_up(v.w, off));
}
__device__ inline float4 shfl_up4w(float4 v, int off, int w) {
    return make_float4(__shfl_up(v.x, off, w), __shfl_up(v.y, off, w),
                       __shfl_up(v.z, off, w), __shfl_up(v.w, off, w));
}
__device__ inline unsigned int packh2(float a, float b) {
    __half2 h = __floats2half2_rn(a, b);
    return *reinterpret_cast<unsigned int*>(&h);
}
__device__ inline float2 unpackh2(unsigned int w) {
    __half2 h = *reinterpret_cast<__half2*>(&w);
    return make_float2(__low2float(h), __high2float(h));
}

// Stage 1: per-(batch, chunk) partials: Xs = x0+x1+x2 (stored), sum(Xs), sum(y0),
// chunk max/argmax of x0 (first-occurrence). Block 0 zeroes the output.
__global__ __launch_bounds__(256) void partial_kernel(const float* __restrict__ X,
                                                      const float* __restrict__ Y,
                                                      float* __restrict__ Xs,
                                                      float* __restrict__ Pmax,
                                                      int* __restrict__ Pidx,
                                                      float* __restrict__ Psx,
                                                      float* __restrict__ Psy,
                                                      float* __restrict__ out) {
    const int blk = blockIdx.x;
    const int b = blk >> 5, c = blk & 31;
    const int tid = threadIdx.x, lane = tid & 63, wid = tid >> 6;
    if (blk == 0 && tid == 0) out[0] = 0.0f;  // consumed only by wproj (later kernel)
    const float* xb = X + (size_t)b * 3 * HW;
    const float* yb = Y + (size_t)b * 3 * HW;
    const int base = c * CHLEN;

    float mv = -INFINITY;
    int mi = 0;
    float sx = 0.0f, sy = 0.0f;
#pragma unroll
    for (int k = 0; k < 2; ++k) {
        int p = base + k * 256 + tid;
        float x0 = xb[p], x1 = xb[HW + p], x2 = xb[2 * HW + p], y0 = yb[p];
        float s = x0 + x1 + x2;
        Xs[(size_t)b * HW + p] = s;
        sx += s;
        sy += y0;
        if (x0 > mv) { mv = x0; mi = p; }   // strict > keeps earliest p
    }
#pragma unroll
    for (int off = 32; off > 0; off >>= 1) {
        float ov = __shfl_down(mv, off);
        int oi = __shfl_down(mi, off);
        sx += __shfl_down(sx, off);
        sy += __shfl_down(sy, off);
        if (ov > mv || (ov == mv && oi < mi)) { mv = ov; mi = oi; }
    }
    __shared__ float lmv[4], lsx[4], lsy[4];
    __shared__ int lmi[4];
    if (lane == 0) { lmv[wid] = mv; lmi[wid] = mi; lsx[wid] = sx; lsy[wid] = sy; }
    __syncthreads();
    if (tid == 0) {
        for (int w = 1; w < 4; ++w) {
            if (lmv[w] > lmv[0] || (lmv[w] == lmv[0] && lmi[w] < lmi[0])) {
                lmv[0] = lmv[w];
                lmi[0] = lmi[w];
            }
            lsx[0] += lsx[w];
            lsy[0] += lsy[w];
        }
        Pmax[blk] = lmv[0];
        Pidx[blk] = lmi[0];
        Psx[blk] = lsx[0];
        Psy[blk] = lsy[0];
    }
}

// Stage 2 (combine folded in): every block redundantly reduces the 8x32 partials,
// then builds Zh[p] = packed fp16 x8: (Xs+fix)*invX - Y0*invY, pixel-major 16B.
__global__ __launch_bounds__(256) void zprep_kernel(const float* __restrict__ Pmax,
                                                    const int* __restrict__ Pidx,
                                                    const float* __restrict__ Psx,
                                                    const float* __restrict__ Psy,
                                                    const float* __restrict__ Xs,
                                                    const float* __restrict__ Y,
                                                    uint4* __restrict__ Zh) {
    __shared__ float sInvX[8], sInvY[8], sFa[8];
    __shared__ int sFi[8];
    const int tid = threadIdx.x;
    const int c = tid & 31;
    {
        const int b = tid >> 5;
        float mv = Pmax[tid];
        int mi = Pidx[tid];
        float sx = Psx[tid];
        float sy = Psy[tid];
#pragma unroll
        for (int off = 16; off > 0; off >>= 1) {
            float ov = __shfl_down(mv, off, 32);
            int oi = __shfl_down(mi, off, 32);
            float osx = __shfl_down(sx, off, 32);
            float osy = __shfl_down(sy, off, 32);
            if (ov > mv || (ov == mv && oi < mi)) { mv = ov; mi = oi; }
            sx += osx;
            sy += osy;
        }
        if (c == 0) {
            float fa = (mv < EPSV) ? (EPSV - mv) : 0.0f;
            sFa[b] = fa;
            sFi[b] = mi;
            sInvX[b] = 1.0f / (sx + fa);
            sInvY[b] = 1.0f / sy;
        }
    }
    __syncthreads();
    const int p = blockIdx.x * 256 + tid;
    float z[8];
#pragma unroll
    for (int b = 0; b < 8; ++b) {
        float s = Xs[(size_t)b * HW + p];
        if (p == sFi[b]) s += sFa[b];
        z[b] = s * sInvX[b] - Y[(size_t)b * 3 * HW + p] * sInvY[b];
    }
    Zh[p] = make_uint4(packh2(z[0], z[1]), packh2(z[2], z[3]),
                       packh2(z[4], z[5]), packh2(z[6], z[7]));
}

// Two blocks per projection (half h owns sorted positions [h*8192,(h+1)*8192)).
// Phase 1 (prefix-table ranksort): wsum(i2,j2) = P[i2+128][j2] - P[i2][j2] with
// P built cooperatively (32 clamp terms/thread + packed 8-partial scan) -- ~2.2x
// fewer LDS instructions than the sliding-window version. Ties via register
// bitmask + scanned carry. Phase 2: one 16B fp16x8 gather per pixel, dpc
// precomputed, 16-lane shuffle second-level scan. Cross-half carry via sum(Z)=0.
__global__ __launch_bounds__(1024)
__attribute__((amdgpu_waves_per_eu(4, 4)))
void wproj_kernel(const float* __restrict__ proj,
                  const uint4* __restrict__ Zh,
                  float* __restrict__ out) {
    __shared__ int ce[255];                 // c*2 | e  (c = clamped ceil(d*r))
    __shared__ unsigned short Ptab[256 * 128];  // 64 KiB prefix table
    __shared__ int psum[8 * 128];           // packed (clsum<<5 | tiecnt)
    __shared__ unsigned short sidT[8192];   // 16 KiB own half, [(q&7)*1024 + (q>>3)]
    __shared__ float4 lw[17];
    __shared__ float lred[16];
    __shared__ int sBound;                  // pixel id at global sorted pos 8192

    const int jp = blockIdx.x >> 1;
    const int h = blockIdx.x & 1;
    const int tid = threadIdx.x, lane = tid & 63, wid = tid >> 6;
    float a = proj[jp];
    float b = proj[NPROJ + jp];
    float inv = 1.0f / sqrtf(a * a + b * b);
    const float an = a * inv, bn = b * inv;
    const float ap = fabsf(an), bp = fabsf(bn);
    const bool flipi = (an < 0.0f), flipj = (bn < 0.0f);

    if (bp == 0.0f) {
        for (int t = tid; t < HW; t += 1024) {
            int i2 = t >> 7, j2 = t & 127;
            int ii = flipi ? 127 - i2 : i2;
            int jj = flipj ? 127 - j2 : j2;
            int idv = ii * 128 + jj;
            if (t == 8192) sBound = idv;
            int q = t - (h << 13);
            if ((unsigned)q < 8192u)
                sidT[(q & 7) * 1024 + (q >> 3)] = (unsigned short)idv;
        }
        __syncthreads();
    } else {
        if (tid < 255) {
            int d = tid - 127;
            double v = (double)d * ((double)ap / (double)bp);
            double cv = ceil(v);
            int e = (cv == v) ? 1 : 0;
            int c = (int)fmin(fmax(cv, -128.0), 129.0);
            ce[tid] = c * 2 + e;   // c = val>>1 (arith), e = val&1
        }
        __syncthreads();

        const int j2 = tid & 127;
        const int g = tid >> 7;          // 0..7
        const int jj = flipj ? 127 - j2 : j2;

        // B1: local clamp-prefix over dd in [32g, 32g+32); tie mask for
        // i2p in (16g, 16g+16]
        int lp[32];
        int tmask = 0;
        {
            int run = 0;
            const int dd0 = g * 32;
#pragma unroll
            for (int q = 0; q < 32; ++q) {
                int dd = dd0 + q;
                int cl = 0;
                if (dd < 255) {
                    int c = ce[dd] >> 1;
                    cl = min(max(c + j2, 0), 128);
                }
                run += cl;
                lp[q] = run;
            }
            int tcnt = 0;
#pragma unroll
            for (int q = 1; q <= 16; ++q) {
                int i2p = g * 16 + q;
                if (i2p <= 127) {
                    int v = ce[i2p + 127];
                    if (v & 1) {
                        int tj = j2 + (v >> 1);
                        if (tj >= 0 && tj < 128) { tmask |= (1 << q); tcnt++; }
                    }
                }
            }
            psum[g * 128 + j2] = (run << 5) | tcnt;
        }
        __syncthreads();

        // B2: scan the 8 packed partials; write P entries
        int carryP = 0, carryT = 0;
        for (int g2 = 0; g2 < g; ++g2) {
            int v = psum[g2 * 128 + j2];
            carryP += (v >> 5);
            carryT += (v & 31);
        }
        if (g == 0) Ptab[j2] = 0;  // P[0][j2]
        {
            const int dd0 = g * 32;
#pragma unroll
            for (int q = 0; q < 32; ++q) {
                int dd = dd0 + q;
                if (dd < 255)
                    Ptab[(dd + 1) * 128 + j2] = (unsigned short)(carryP + lp[q]);
            }
        }
        __syncthreads();

        // D: ranks for i2 in [16g, 16g+16)
        int tsum = carryT;
        const int i2s = g * 16;
#pragma unroll
        for (int q = 0; q < 16; ++q) {
            int i2 = i2s + q;
            if (q > 0) tsum += (tmask >> q) & 1;
            int wsum = (int)Ptab[(i2 + 128) * 128 + j2] - (int)Ptab[i2 * 128 + j2];
            int pos = wsum + tsum;
            int ii = flipi ? 127 - i2 : i2;
            int idv = ii * 128 + jj;
            if (pos == 8192) sBound = idv;
            int ql = pos - (h << 13);
            if ((unsigned)ql < 8192u)
                sidT[(ql & 7) * 1024 + (ql >> 3)] = (unsigned short)idv;
        }
        __syncthreads();
    }

    // ---- phase 2: thread owns local positions [8*tid, 8*tid+7] ----
    int ids[9];
#pragma unroll
    for (int m = 0; m < 8; ++m) ids[m] = (int)sidT[m * 1024 + tid];
    ids[8] = (tid < 1023) ? (int)sidT[tid + 1]
                          : ((h == 0) ? sBound : ids[7]);  // h==1 tail: dpc[7]=0

    float dpc[8];
    {
        float pc_cur = (float)(ids[0] >> 7) * an + (float)(ids[0] & 127) * bn;
#pragma unroll
        for (int m = 0; m < 8; ++m) {
            int idn = ids[m + 1];
            float pc_nxt = (float)(idn >> 7) * an + (float)(idn & 127) * bn;
            dpc[m] = pc_nxt - pc_cur;
            pc_cur = pc_nxt;
        }
    }

    // single 16B gather per pixel: all 8 channels packed fp16
    uint4 raw[8];
#pragma unroll
    for (int m = 0; m < 8; ++m) raw[m] = Zh[ids[m]];

    float acc = 0.0f;
#pragma unroll 1
    for (int cg = 0; cg < 2; ++cg) {
        float4 zv[8];
#pragma unroll
        for (int m = 0; m < 8; ++m) {
            unsigned int d0 = (cg == 0) ? raw[m].x : raw[m].z;
            unsigned int d1 = (cg == 0) ? raw[m].y : raw[m].w;
            float2 f0 = unpackh2(d0);
            float2 f1 = unpackh2(d1);
            zv[m] = make_float4(f0.x, f0.y, f1.x, f1.y);
        }
#pragma unroll
        for (int m = 1; m < 8; ++m) zv[m] = add4(zv[m], zv[m - 1]);
        const float4 tot = zv[7];

        float4 ia = tot;
#pragma unroll
        for (int off = 1; off < 64; off <<= 1) {
            float4 ua = shfl_up4(ia, off);
            if (lane >= off) ia = add4(ia, ua);
        }
        if (lane == 63) lw[wid] = ia;
        __syncthreads();
        if (tid < 16) {  // second-level 16-lane scan of wave totals
            float4 v = lw[tid];
            float4 s = v;
#pragma unroll
            for (int off = 1; off < 16; off <<= 1) {
                float4 u = shfl_up4w(s, off, 16);
                if (tid >= off) s = add4(s, u);
            }
            lw[tid] = sub4(s, v);       // exclusive
            if (tid == 15) lw[16] = s;  // block total
        }
        __syncthreads();

        float4 pre = add4(sub4(ia, tot), lw[wid]);
        if (h == 1) pre = sub4(pre, lw[16]);  // carry = total(h0) = -total(h1)

#pragma unroll
        for (int m = 0; m < 8; ++m) {
            float4 cx = add4(pre, zv[m]);
            acc += (fabsf(cx.x) + fabsf(cx.y) + fabsf(cx.z) + fabsf(cx.w)) * dpc[m];
        }
        __syncthreads();  // protect lw reuse in next pass
    }

    // block reduce
#pragma unroll
    for (int off = 32; off > 0; off >>= 1) acc += __shfl_down(acc, off);
    if (lane == 0) lred[wid] = acc;
    __syncthreads();
    if (tid == 0) {
        float r = 0.0f;
        for (int w = 0; w < 16; ++w) r += lred[w];
        atomicAdd(out, r * (1.0f / NPROJ));
    }
}

extern "C" void kernel_launch(void* const* d_in, const int* in_sizes, int n_in,
                              void* d_out, int out_size, void* d_ws, size_t ws_size,
                              hipStream_t stream) {
    const float* X = (const float*)d_in[0];
    const float* Y = (const float*)d_in[1];
    const float* proj = (const float*)d_in[2];
    float* out = (float*)d_out;

    char* ws = (char*)d_ws;
    size_t off = 0;
    float* Xs = (float*)(ws + off);     off += (size_t)NB * HW * sizeof(float);
    uint4* Zh = (uint4*)(ws + off);     off += (size_t)HW * sizeof(uint4);
    float* Pmax = (float*)(ws + off);   off += NB * NCH * sizeof(float);
    int* Pidx = (int*)(ws + off);       off += NB * NCH * sizeof(int);
    float* Psx = (float*)(ws + off);    off += NB * NCH * sizeof(float);
    float* Psy = (float*)(ws + off);    off += NB * NCH * sizeof(float);

    partial_kernel<<<NB * NCH, 256, 0, stream>>>(X, Y, Xs, Pmax, Pidx, Psx, Psy, out);
    zprep_kernel<<<HW / 256, 256, 0, stream>>>(Pmax, Pidx, Psx, Psy, Xs, Y, Zh);
    wproj_kernel<<<NPROJ * 2, 1024, 0, stream>>>(proj, Zh, out);
}

// Round 14
// 26.198 us; speedup vs baseline: 1.5727x; 1.0801x over previous
//
#include <hip/hip_runtime.h>
#include <hip/hip_fp16.h>
#include <math.h>

#define HW 16384
#define NPROJ 100
#define NB 8
#define NCH 32
#define CHLEN 512
#define EPSV 1e-6f

__device__ inline float4 add4(float4 a, float4 b) {
    return make_float4(a.x + b.x, a.y + b.y, a.z + b.z, a.w + b.w);
}
__device__ inline float4 sub4(float4 a, float4 b) {
    return make_float4(a.x - b.x, a.y - b.y, a.z - b.z, a.w - b.w);
}
__device__ inline float4 shfl_up4(float4 v, int off) {
    return make_float4(__shfl_up(v.x, off), __shfl_up(v.y, off),
                       __shfl_up(v.z, off), __shfl_up(v.w, off));
}
__device__ inline float4 shfl_up4w(float4 v, int off, int w) {
    return make_float4(__shfl_up(v.x, off, w), __shfl_up(v.y, off, w),
                       __shfl_up(v.z, off, w), __shfl_up(v.w, off, w));
}
__device__ inline unsigned int packh2(float a, float b) {
    __half2 h = __floats2half2_rn(a, b);
    return *reinterpret_cast<unsigned int*>(&h);
}
__device__ inline float2 unpackh2(unsigned int w) {
    __half2 h = *reinterpret_cast<__half2*>(&w);
    return make_float2(__low2float(h), __high2float(h));
}

// Stage 1: per-(batch, chunk) partials: Xs = x0+x1+x2 (stored), sum(Xs), sum(y0),
// chunk max/argmax of x0 (first-occurrence). Block 0 zeroes the output.
__global__ __launch_bounds__(256) void partial_kernel(const float* __restrict__ X,
                                                      const float* __restrict__ Y,
                                                      float* __restrict__ Xs,
                                                      float* __restrict__ Pmax,
                                                      int* __restrict__ Pidx,
                                                      float* __restrict__ Psx,
                                                      float* __restrict__ Psy,
                                                      float* __restrict__ out) {
    const int blk = blockIdx.x;
    const int b = blk >> 5, c = blk & 31;
    const int tid = threadIdx.x, lane = tid & 63, wid = tid >> 6;
    if (blk == 0 && tid == 0) out[0] = 0.0f;  // consumed only by wproj (later kernel)
    const float* xb = X + (size_t)b * 3 * HW;
    const float* yb = Y + (size_t)b * 3 * HW;
    const int base = c * CHLEN;

    float mv = -INFINITY;
    int mi = 0;
    float sx = 0.0f, sy = 0.0f;
#pragma unroll
    for (int k = 0; k < 2; ++k) {
        int p = base + k * 256 + tid;
        float x0 = xb[p], x1 = xb[HW + p], x2 = xb[2 * HW + p], y0 = yb[p];
        float s = x0 + x1 + x2;
        Xs[(size_t)b * HW + p] = s;
        sx += s;
        sy += y0;
        if (x0 > mv) { mv = x0; mi = p; }   // strict > keeps earliest p
    }
#pragma unroll
    for (int off = 32; off > 0; off >>= 1) {
        float ov = __shfl_down(mv, off);
        int oi = __shfl_down(mi, off);
        sx += __shfl_down(sx, off);
        sy += __shfl_down(sy, off);
        if (ov > mv || (ov == mv && oi < mi)) { mv = ov; mi = oi; }
    }
    __shared__ float lmv[4], lsx[4], lsy[4];
    __shared__ int lmi[4];
    if (lane == 0) { lmv[wid] = mv; lmi[wid] = mi; lsx[wid] = sx; lsy[wid] = sy; }
    __syncthreads();
    if (tid == 0) {
        for (int w = 1; w < 4; ++w) {
            if (lmv[w] > lmv[0] || (lmv[w] == lmv[0] && lmi[w] < lmi[0])) {
                lmv[0] = lmv[w];
                lmi[0] = lmi[w];
            }
            lsx[0] += lsx[w];
            lsy[0] += lsy[w];
        }
        Pmax[blk] = lmv[0];
        Pidx[blk] = lmi[0];
        Psx[blk] = lsx[0];
        Psy[blk] = lsy[0];
    }
}

// Stage 2 (combine folded in): every block redundantly reduces the 8x32 partials,
// then builds Zh[p] = packed fp16 x8: (Xs+fix)*invX - Y0*invY, pixel-major 16B.
__global__ __launch_bounds__(256) void zprep_kernel(const float* __restrict__ Pmax,
                                                    const int* __restrict__ Pidx,
                                                    const float* __restrict__ Psx,
                                                    const float* __restrict__ Psy,
                                                    const float* __restrict__ Xs,
                                                    const float* __restrict__ Y,
                                                    uint4* __restrict__ Zh) {
    __shared__ float sInvX[8], sInvY[8], sFa[8];
    __shared__ int sFi[8];
    const int tid = threadIdx.x;
    const int c = tid & 31;
    {
        const int b = tid >> 5;
        float mv = Pmax[tid];
        int mi = Pidx[tid];
        float sx = Psx[tid];
        float sy = Psy[tid];
#pragma unroll
        for (int off = 16; off > 0; off >>= 1) {
            float ov = __shfl_down(mv, off, 32);
            int oi = __shfl_down(mi, off, 32);
            float osx = __shfl_down(sx, off, 32);
            float osy = __shfl_down(sy, off, 32);
            if (ov > mv || (ov == mv && oi < mi)) { mv = ov; mi = oi; }
            sx += osx;
            sy += osy;
        }
        if (c == 0) {
            float fa = (mv < EPSV) ? (EPSV - mv) : 0.0f;
            sFa[b] = fa;
            sFi[b] = mi;
            sInvX[b] = 1.0f / (sx + fa);
            sInvY[b] = 1.0f / sy;
        }
    }
    __syncthreads();
    const int p = blockIdx.x * 256 + tid;
    float z[8];
#pragma unroll
    for (int b = 0; b < 8; ++b) {
        float s = Xs[(size_t)b * HW + p];
        if (p == sFi[b]) s += sFa[b];
        z[b] = s * sInvX[b] - Y[(size_t)b * 3 * HW + p] * sInvY[b];
    }
    Zh[p] = make_uint4(packh2(z[0], z[1]), packh2(z[2], z[3]),
                       packh2(z[4], z[5]), packh2(z[6], z[7]));
}

// Two blocks per projection (half h owns sorted positions [h*8192,(h+1)*8192)).
// Phase 1 (prefix-table ranksort): wsum(i2,j2) = P[i2+128][j2] - P[i2][j2];
// tie logic skipped entirely when no d*r (d>=1) is exactly integral (sAnyTie,
// always the case for random projections). Phase 2: one 16B fp16x8 gather per
// pixel, SINGLE-pass 8-channel register scan (zva/zvb float4 pairs, ~105 VGPR
// under the waves_per_eu(4,4) 128 budget), one barrier pair + one second-level
// scan instead of two. Cross-half carry via sum(Z)=0.
__global__ __launch_bounds__(1024)
__attribute__((amdgpu_waves_per_eu(4, 4)))
void wproj_kernel(const float* __restrict__ proj,
                  const uint4* __restrict__ Zh,
                  float* __restrict__ out) {
    __shared__ int ce[255];                 // c*2 | e  (c = clamped ceil(d*r))
    __shared__ unsigned short Ptab[256 * 128];  // 64 KiB prefix table
    __shared__ int psum[8 * 128];           // per-group clamp sums
    __shared__ unsigned short sidT[8192];   // 16 KiB own half, [(q&7)*1024 + (q>>3)]
    __shared__ float4 lwa[17], lwb[17];
    __shared__ float lred[16];
    __shared__ int sBound;                  // pixel id at global sorted pos 8192
    __shared__ int sAnyTie;

    const int jp = blockIdx.x >> 1;
    const int h = blockIdx.x & 1;
    const int tid = threadIdx.x, lane = tid & 63, wid = tid >> 6;
    float a = proj[jp];
    float b = proj[NPROJ + jp];
    float inv = 1.0f / sqrtf(a * a + b * b);
    const float an = a * inv, bn = b * inv;
    const float ap = fabsf(an), bp = fabsf(bn);
    const bool flipi = (an < 0.0f), flipj = (bn < 0.0f);

    if (bp == 0.0f) {
        for (int t = tid; t < HW; t += 1024) {
            int i2 = t >> 7, j2 = t & 127;
            int ii = flipi ? 127 - i2 : i2;
            int jj = flipj ? 127 - j2 : j2;
            int idv = ii * 128 + jj;
            if (t == 8192) sBound = idv;
            int q = t - (h << 13);
            if ((unsigned)q < 8192u)
                sidT[(q & 7) * 1024 + (q >> 3)] = (unsigned short)idv;
        }
        __syncthreads();
    } else {
        if (tid == 0) sAnyTie = 0;
        // (covered by the barrier below)
        if (tid < 255) {
            int d = tid - 127;
            double v = (double)d * ((double)ap / (double)bp);
            double cv = ceil(v);
            int e = (cv == v) ? 1 : 0;
            int c = (int)fmin(fmax(cv, -128.0), 129.0);
            ce[tid] = c * 2 + e;   // c = val>>1 (arith), e = val&1
            if (e && d >= 1) sAnyTie = 1;  // benign same-value race
        }
        __syncthreads();

        const int j2 = tid & 127;
        const int g = tid >> 7;          // 0..7
        const int jj = flipj ? 127 - j2 : j2;
        const bool anyTie = (sAnyTie != 0);

        // B1: local clamp-prefix over dd in [32g, 32g+32); tie mask for
        // i2p in (16g, 16g+16] (skipped when no ties exist)
        int lp[32];
        int tmask = 0;
        {
            int run = 0;
            const int dd0 = g * 32;
#pragma unroll
            for (int q = 0; q < 32; ++q) {
                int dd = dd0 + q;
                int cl = 0;
                if (dd < 255) {
                    int c = ce[dd] >> 1;
                    cl = min(max(c + j2, 0), 128);
                }
                run += cl;
                lp[q] = run;
            }
            int tcnt = 0;
            if (anyTie) {
#pragma unroll
                for (int q = 1; q <= 16; ++q) {
                    int i2p = g * 16 + q;
                    if (i2p <= 127) {
                        int v = ce[i2p + 127];
                        if (v & 1) {
                            int tj = j2 + (v >> 1);
                            if (tj >= 0 && tj < 128) { tmask |= (1 << q); tcnt++; }
                        }
                    }
                }
            }
            psum[g * 128 + j2] = (run << 5) | tcnt;
        }
        __syncthreads();

        // B2: scan the 8 packed partials; write P entries
        int carryP = 0, carryT = 0;
        for (int g2 = 0; g2 < g; ++g2) {
            int v = psum[g2 * 128 + j2];
            carryP += (v >> 5);
            carryT += (v & 31);
        }
        if (g == 0) Ptab[j2] = 0;  // P[0][j2]
        {
            const int dd0 = g * 32;
#pragma unroll
            for (int q = 0; q < 32; ++q) {
                int dd = dd0 + q;
                if (dd < 255)
                    Ptab[(dd + 1) * 128 + j2] = (unsigned short)(carryP + lp[q]);
            }
        }
        __syncthreads();

        // D: ranks for i2 in [16g, 16g+16)
        int tsum = carryT;
        const int i2s = g * 16;
#pragma unroll
        for (int q = 0; q < 16; ++q) {
            int i2 = i2s + q;
            if (q > 0) tsum += (tmask >> q) & 1;
            int wsum = (int)Ptab[(i2 + 128) * 128 + j2] - (int)Ptab[i2 * 128 + j2];
            int pos = wsum + tsum;
            int ii = flipi ? 127 - i2 : i2;
            int idv = ii * 128 + jj;
            if (pos == 8192) sBound = idv;
            int ql = pos - (h << 13);
            if ((unsigned)ql < 8192u)
                sidT[(ql & 7) * 1024 + (ql >> 3)] = (unsigned short)idv;
        }
        __syncthreads();
    }

    // ---- phase 2: thread owns local positions [8*tid, 8*tid+7] ----
    int ids[9];
#pragma unroll
    for (int m = 0; m < 8; ++m) ids[m] = (int)sidT[m * 1024 + tid];
    ids[8] = (tid < 1023) ? (int)sidT[tid + 1]
                          : ((h == 0) ? sBound : ids[7]);  // h==1 tail: dpc[7]=0

    float dpc[8];
    {
        float pc_cur = (float)(ids[0] >> 7) * an + (float)(ids[0] & 127) * bn;
#pragma unroll
        for (int m = 0; m < 8; ++m) {
            int idn = ids[m + 1];
            float pc_nxt = (float)(idn >> 7) * an + (float)(idn & 127) * bn;
            dpc[m] = pc_nxt - pc_cur;
            pc_cur = pc_nxt;
        }
    }

    // single 16B gather per pixel; unpack to 8-channel register state
    float4 zva[8], zvb[8];
#pragma unroll
    for (int m = 0; m < 8; ++m) {
        uint4 r = Zh[ids[m]];
        float2 f0 = unpackh2(r.x);
        float2 f1 = unpackh2(r.y);
        float2 f2 = unpackh2(r.z);
        float2 f3 = unpackh2(r.w);
        zva[m] = make_float4(f0.x, f0.y, f1.x, f1.y);
        zvb[m] = make_float4(f2.x, f2.y, f3.x, f3.y);
    }
#pragma unroll
    for (int m = 1; m < 8; ++m) {
        zva[m] = add4(zva[m], zva[m - 1]);
        zvb[m] = add4(zvb[m], zvb[m - 1]);
    }
    const float4 tota = zva[7], totb = zvb[7];

    float4 ia = tota, ib = totb;
#pragma unroll
    for (int off = 1; off < 64; off <<= 1) {
        float4 ua = shfl_up4(ia, off);
        float4 ub = shfl_up4(ib, off);
        if (lane >= off) { ia = add4(ia, ua); ib = add4(ib, ub); }
    }
    if (lane == 63) { lwa[wid] = ia; lwb[wid] = ib; }
    __syncthreads();
    if (tid < 16) {  // second-level 16-lane scan of wave totals
        float4 va = lwa[tid], vb = lwb[tid];
        float4 sa = va, sb = vb;
#pragma unroll
        for (int off = 1; off < 16; off <<= 1) {
            float4 ua = shfl_up4w(sa, off, 16);
            float4 ub = shfl_up4w(sb, off, 16);
            if (tid >= off) { sa = add4(sa, ua); sb = add4(sb, ub); }
        }
        lwa[tid] = sub4(sa, va);       // exclusive
        lwb[tid] = sub4(sb, vb);
        if (tid == 15) { lwa[16] = sa; lwb[16] = sb; }  // block totals
    }
    __syncthreads();

    float4 preA = add4(sub4(ia, tota), lwa[wid]);
    float4 preB = add4(sub4(ib, totb), lwb[wid]);
    if (h == 1) {  // carry = total(h0) = -total(h1)
        preA = sub4(preA, lwa[16]);
        preB = sub4(preB, lwb[16]);
    }

    float acc = 0.0f;
#pragma unroll
    for (int m = 0; m < 8; ++m) {
        float4 cxa = add4(preA, zva[m]);
        float4 cxb = add4(preB, zvb[m]);
        float s8 = fabsf(cxa.x) + fabsf(cxa.y) + fabsf(cxa.z) + fabsf(cxa.w)
                 + fabsf(cxb.x) + fabsf(cxb.y) + fabsf(cxb.z) + fabsf(cxb.w);
        acc += s8 * dpc[m];
    }

    // block reduce
#pragma unroll
    for (int off = 32; off > 0; off >>= 1) acc += __shfl_down(acc, off);
    if (lane == 0) lred[wid] = acc;
    __syncthreads();
    if (tid == 0) {
        float r = 0.0f;
        for (int w = 0; w < 16; ++w) r += lred[w];
        atomicAdd(out, r * (1.0f / NPROJ));
    }
}

extern "C" void kernel_launch(void* const* d_in, const int* in_sizes, int n_in,
                              void* d_out, int out_size, void* d_ws, size_t ws_size,
                              hipStream_t stream) {
    const float* X = (const float*)d_in[0];
    const float* Y = (const float*)d_in[1];
    const float* proj = (const float*)d_in[2];
    float* out = (float*)d_out;

    char* ws = (char*)d_ws;
    size_t off = 0;
    float* Xs = (float*)(ws + off);     off += (size_t)NB * HW * sizeof(float);
    uint4* Zh = (uint4*)(ws + off);     off += (size_t)HW * sizeof(uint4);
    float* Pmax = (float*)(ws + off);   off += NB * NCH * sizeof(float);
    int* Pidx = (int*)(ws + off);       off += NB * NCH * sizeof(int);
    float* Psx = (float*)(ws + off);    off += NB * NCH * sizeof(float);
    float* Psy = (float*)(ws + off);    off += NB * NCH * sizeof(float);

    partial_kernel<<<NB * NCH, 256, 0, stream>>>(X, Y, Xs, Pmax, Pidx, Psx, Psy, out);
    zprep_kernel<<<HW / 256, 256, 0, stream>>>(Pmax, Pidx, Psx, Psy, Xs, Y, Zh);
    wproj_kernel<<<NPROJ * 2, 1024, 0, stream>>>(proj, Zh, out);
}